// Round 2
// baseline (368.609 us; speedup 1.0000x reference)
//
#include <hip/hip_runtime.h>

constexpr int NB  = 2;     // batch
constexpr int NCI = 4;     // conv input channels
constexpr int NHH = 256;   // H
constexpr int NWW = 256;   // W
constexpr int NCT = 1024;  // conv output channels

// workspace layout (floats)
constexpr int G_OFF   = 0;
constexpr int G_SIZE  = 3 * NB * NCI * NHH * 48;   // 294912  G[m][b][i][h][dx*16+r]
constexpr int SW1_OFF = G_OFF + G_SIZE;            // 3*16 column sums of W1
constexpr int Q_OFF   = SW1_OFF + 48;
constexpr int QKV_ONE = NB * 4 * NCT * 64;         // 524288
constexpr int K_OFF   = Q_OFF + QKV_ONE;           // k stored transposed [x][o]
constexpr int V_OFF   = K_OFF + QKV_ONE;

__device__ __forceinline__ float sigmoid_f(float v) {
  return __builtin_amdgcn_rcpf(1.0f + __expf(-v));
}

// K1: G[m][b][i][h][dx*16+r] = sum_w x_pad[b,i,h,w+dx-1] * W1_m[w,r]
// grid: 3*NB*NCI*(NHH/4) + 3, block 64   (unchanged from R1)
__global__ __launch_bounds__(64) void k1_G(
    const float* __restrict__ x,
    const float* __restrict__ qW1, const float* __restrict__ kW1,
    const float* __restrict__ vW1, float* __restrict__ ws) {
  const int tid = threadIdx.x;
  const int NBLK = 3 * NB * NCI * (NHH / 4);
  int bid = blockIdx.x;
  if (bid >= NBLK) {  // column sums of W1 (for conv_b term)
    int m = bid - NBLK;
    if (tid < 16) {
      const float* W1 = (m == 0) ? qW1 : (m == 1) ? kW1 : vW1;
      float s = 0.f;
      for (int w = 0; w < 256; ++w) s += W1[w * 16 + tid];
      ws[SW1_OFF + m * 16 + tid] = s;
    }
    return;
  }
  const int m  = bid / (NB * NCI * (NHH / 4));
  int rem      = bid % (NB * NCI * (NHH / 4));
  const int b  = rem / (NCI * (NHH / 4));
  rem          = rem % (NCI * (NHH / 4));
  const int i  = rem / (NHH / 4);
  const int h0 = (rem % (NHH / 4)) * 4;

  const float* W1 = (m == 0) ? qW1 : (m == 1) ? kW1 : vW1;

  __shared__ float W1l[16 * 260];
  __shared__ float xlb[4][260];

  for (int idx4 = tid; idx4 < 1024; idx4 += 64) {
    const float4 t = ((const float4*)W1)[idx4];
    const int w = idx4 >> 2, r0 = (idx4 & 3) * 4;
    W1l[(r0 + 0) * 260 + w] = t.x;
    W1l[(r0 + 1) * 260 + w] = t.y;
    W1l[(r0 + 2) * 260 + w] = t.z;
    W1l[(r0 + 3) * 260 + w] = t.w;
  }
  const float* xbase = x + ((size_t)(b * NCI + i) * NHH + h0) * NWW;
  for (int idx = tid; idx < 4 * 256; idx += 64) {
    const int rr = idx >> 8, w = idx & 255;
    xlb[rr][1 + w] = xbase[rr * NWW + w];
  }
  if (tid < 4) {
    xlb[tid][0] = 0.f; xlb[tid][257] = 0.f; xlb[tid][258] = 0.f; xlb[tid][259] = 0.f;
  }
  __syncthreads();

  const int wc = tid >> 4, r = tid & 15;
  const int w0 = wc * 64;
  float* Gw = ws + G_OFF + ((size_t)(m * NB + b) * NCI + i) * NHH * 48;
  #pragma unroll
  for (int rr = 0; rr < 4; ++rr) {
    const float* xl = xlb[rr];
    float a0 = 0.f, a1 = 0.f, a2 = 0.f;
    float4 cur = *(const float4*)&xl[w0];
    #pragma unroll 4
    for (int w = w0; w < w0 + 64; w += 4) {
      const float4 nxt = *(const float4*)&xl[w + 4];
      const float4 w1  = *(const float4*)&W1l[r * 260 + w];
      a0 += w1.x * cur.x + w1.y * cur.y + w1.z * cur.z + w1.w * cur.w;
      a1 += w1.x * cur.y + w1.y * cur.z + w1.z * cur.w + w1.w * nxt.x;
      a2 += w1.x * cur.z + w1.y * cur.w + w1.z * nxt.x + w1.w * nxt.y;
      cur = nxt;
    }
    a0 += __shfl_xor(a0, 16, 64); a0 += __shfl_xor(a0, 32, 64);
    a1 += __shfl_xor(a1, 16, 64); a1 += __shfl_xor(a1, 32, 64);
    a2 += __shfl_xor(a2, 16, 64); a2 += __shfl_xor(a2, 32, 64);
    if (wc == 0) {
      float* g = Gw + (size_t)(h0 + rr) * 48;
      g[r] = a0; g[16 + r] = a1; g[32 + r] = a2;
    }
  }
}

// K2 (rewritten): GEMM-ized layer1 (K=36, cw via scalar loads) + in-register layer2.
// grid 768 = NB*3*128 (8 o per block), block 512 = 8 waves.
// Per tile (32 h): stage G rows [h0-1..h0+32] -> LDS [i][34][49], 2 barriers.
__global__ __launch_bounds__(512) void k2_mlp(
    const float* __restrict__ conv_w, const float* __restrict__ conv_b,
    const float* __restrict__ qb1, const float* __restrict__ qW2, const float* __restrict__ qb2,
    const float* __restrict__ kb1, const float* __restrict__ kW2, const float* __restrict__ kb2,
    const float* __restrict__ vb1, const float* __restrict__ vW2, const float* __restrict__ vb2,
    float* __restrict__ ws) {
  const int tid = threadIdx.x;
  const int bid = blockIdx.x;
  const int og = bid & 127;
  const int m  = (bid >> 7) % 3;
  const int b  = bid / 384;
  const int o0 = og * 8;

  const int w    = tid >> 6;        // wave 0..7
  const int lane = tid & 63;
  const int hc   = lane >> 4;       // 0..3
  const int r    = lane & 15;

  const float* b1 = (m == 0) ? qb1 : (m == 1) ? kb1 : vb1;
  const float* W2 = (m == 0) ? qW2 : (m == 1) ? kW2 : vW2;
  const float* b2 = (m == 0) ? qb2 : (m == 1) ? kb2 : vb2;

  __shared__ float LDS[12296];
  float* Gl  = LDS;            // [i][34][49]  (i-stride 1666, row-stride 49)
  float* y1l = LDS + 6664;     // [o][32][17]  (o-stride 544)
  float* W2l = LDS + 11016;    // [2][32][20]

  const float* Gbase = ws + G_OFF + (size_t)(m * 2 + b) * (4 * 256 * 48);
  const float sw1r = ws[SW1_OFF + m * 16 + r];
  const float b1r  = b1[r];
  float cb[8];
  #pragma unroll
  for (int j = 0; j < 8; ++j) cb[j] = conv_b[o0 + j];

  // phase-2 mapping
  const int p2_o  = tid >> 6;
  const int p2_r  = (tid >> 2) & 15;
  const int p2_sq = tid & 3;

  float acc2[4] = {0.f, 0.f, 0.f, 0.f};

  for (int t = 0; t < 8; ++t) {
    const int h0 = t * 32;
    float* W2b = W2l + (t & 1) * 640;

    // stage G slab (rows h0-1 .. h0+32, zero-padded at edges)
    for (int idx = tid; idx < 6528; idx += 512) {
      const int i = idx / 1632, rem = idx % 1632;
      const int row = rem / 48, c = rem % 48;
      const int h = h0 - 1 + row;
      const float v = (h >= 0 && h < 256) ? Gbase[((size_t)i * 256 + h) * 48 + c] : 0.f;
      Gl[i * 1666 + row * 49 + c] = v;
    }
    { // stage W2 tile
      const int hh = tid >> 4, s = tid & 15;
      W2b[hh * 20 + s] = W2[(h0 + hh) * 16 + s];
    }
    __syncthreads();

    // phase 1: pre-activation for 8 o's at column (h = h0 + w*4 + hc, r)
    {
      float acc[8];
      #pragma unroll
      for (int j = 0; j < 8; ++j) acc[j] = cb[j] * sw1r + b1r;
      const float* gl = Gl + (w * 4 + hc) * 49 + r;
      #pragma unroll 1
      for (int i = 0; i < 4; ++i) {
        float g[9];
        #pragma unroll
        for (int q = 0; q < 9; ++q) {
          const int dy = q / 3, dx = q % 3;
          g[q] = gl[i * 1666 + dy * 49 + dx * 16];
        }
        #pragma unroll 2
        for (int j = 0; j < 8; ++j) {
          const float* cwp = conv_w + (size_t)(o0 + j) * 36 + i * 9;  // uniform -> s_load
          #pragma unroll
          for (int q = 0; q < 9; ++q) acc[j] += cwp[q] * g[q];
        }
      }
      const int hl = w * 4 + hc;
      #pragma unroll
      for (int j = 0; j < 8; ++j) y1l[j * 544 + hl * 17 + r] = sigmoid_f(acc[j]);
    }
    __syncthreads();

    // phase 2: contract y1 over the 32 h of this tile into acc2
    {
      const float* yb = y1l + p2_o * 544 + p2_r;
      const float* wb = W2b + p2_sq * 4;
      #pragma unroll 4
      for (int hh = 0; hh < 32; ++hh) {
        const float y = yb[hh * 17];
        const float4 wv = *(const float4*)&wb[hh * 20];
        acc2[0] += y * wv.x; acc2[1] += y * wv.y;
        acc2[2] += y * wv.z; acc2[3] += y * wv.w;
      }
    }
    // no barrier: next staging writes Gl only; phase2 reads y1l/W2b only
  }

  // epilogue: y2 -> LDS (reuse Gl region) -> coalesced global writes
  #pragma unroll
  for (int j = 0; j < 4; ++j) {
    const int s = p2_sq * 4 + j;
    const float y2 = sigmoid_f(acc2[j] + b2[s]);
    const int n   = (j & 1) * 2 + (p2_r & 1);
    const int xsp = (p2_sq * 2 + (j >> 1)) * 8 + (p2_r >> 1);
    LDS[p2_o * 256 + n * 64 + xsp] = y2;   // y2l[o_loc][n][xsp]
  }
  __syncthreads();

  if (m != 1) {  // q, v: [bn][o][xsp], fully coalesced float4 runs
    float* dst = ws + ((m == 0) ? Q_OFF : V_OFF);
    const int run = tid >> 4, pos = (tid & 15) * 4;
    const int n = run >> 3, o_l = run & 7;
    const float4 v4 = *(const float4*)&LDS[o_l * 256 + n * 64 + pos];
    *(float4*)&dst[((size_t)(b * 4 + n) * 1024 + o0 + o_l) * 64 + pos] = v4;
  } else {       // k: [bn][xsp][o], float4 chunks of 8-o run
    float* dst = ws + K_OFF;
    const int chunk = tid >> 1, half = tid & 1;
    const int n = chunk >> 6, xsp = chunk & 63;
    float4 v4;
    v4.x = LDS[(half * 4 + 0) * 256 + n * 64 + xsp];
    v4.y = LDS[(half * 4 + 1) * 256 + n * 64 + xsp];
    v4.z = LDS[(half * 4 + 2) * 256 + n * 64 + xsp];
    v4.w = LDS[(half * 4 + 3) * 256 + n * 64 + xsp];
    *(float4*)&dst[((size_t)(b * 4 + n) * 64 + xsp) * 1024 + o0 + half * 4] = v4;
  }
}

// K3: per (b,n): scores = q k^T * temp over 64-dim, softmax over e, @ v.
// grid 1024 = 8 bn x 128 row-groups (8 rows), block 256.  (unchanged from R1)
__global__ __launch_bounds__(256) void k3_attn(
    const float* __restrict__ ws, const float* __restrict__ temp,
    float* __restrict__ out) {
  const int tid = threadIdx.x;
  const int bn = blockIdx.x >> 7;
  const int c0 = (blockIdx.x & 127) * 8;
  const float* q  = ws + Q_OFF + (size_t)bn * NCT * 64;
  const float* kT = ws + K_OFF + (size_t)bn * 64 * NCT;
  const float* v  = ws + V_OFF + (size_t)bn * NCT * 64;
  const float tscale = temp[bn & 3];

  __shared__ float S[8 * 1024];
  __shared__ float ql[64 * 8];
  __shared__ float lrow[8];

  for (int j = tid; j < 8 * 64; j += 256) {
    const int c = j >> 6, d = j & 63;
    ql[d * 8 + c] = q[(size_t)(c0 + c) * 64 + d];
  }
  __syncthreads();

  {
    float acc[32];
    #pragma unroll
    for (int j = 0; j < 32; ++j) acc[j] = 0.f;
    for (int d = 0; d < 64; ++d) {
      const float* kr = kT + (size_t)d * NCT;
      const float kv0 = kr[tid];
      const float kv1 = kr[tid + 256];
      const float kv2 = kr[tid + 512];
      const float kv3 = kr[tid + 768];
      #pragma unroll
      for (int c4 = 0; c4 < 2; ++c4) {
        const float4 qv = *(const float4*)&ql[d * 8 + c4 * 4];
        const float qa[4] = {qv.x, qv.y, qv.z, qv.w};
        #pragma unroll
        for (int jj = 0; jj < 4; ++jj) {
          const int cc = c4 * 4 + jj;
          acc[cc * 4 + 0] += qa[jj] * kv0;
          acc[cc * 4 + 1] += qa[jj] * kv1;
          acc[cc * 4 + 2] += qa[jj] * kv2;
          acc[cc * 4 + 3] += qa[jj] * kv3;
        }
      }
    }
    #pragma unroll
    for (int cc = 0; cc < 8; ++cc) {
      S[cc * 1024 + tid      ] = acc[cc * 4 + 0] * tscale;
      S[cc * 1024 + tid + 256] = acc[cc * 4 + 1] * tscale;
      S[cc * 1024 + tid + 512] = acc[cc * 4 + 2] * tscale;
      S[cc * 1024 + tid + 768] = acc[cc * 4 + 3] * tscale;
    }
  }
  __syncthreads();

  {
    const int c = tid >> 5, l = tid & 31;
    float* row = &S[c * 1024];
    float mx = -1e30f;
    for (int j = l; j < 1024; j += 32) mx = fmaxf(mx, row[j]);
    #pragma unroll
    for (int msk = 1; msk < 32; msk <<= 1) mx = fmaxf(mx, __shfl_xor(mx, msk, 64));
    float sum = 0.f;
    for (int j = l; j < 1024; j += 32) {
      const float p = __expf(row[j] - mx);
      row[j] = p;
      sum += p;
    }
    #pragma unroll
    for (int msk = 1; msk < 32; msk <<= 1) sum += __shfl_xor(sum, msk, 64);
    if (l == 0) lrow[c] = sum;
  }
  __syncthreads();

  {
    const int xx = tid & 63, cq = tid >> 6;
    float a0 = 0.f, a1 = 0.f;
    for (int e = 0; e < 1024; e += 4) {
      const float v0 = v[(size_t)(e + 0) * 64 + xx];
      const float v1 = v[(size_t)(e + 1) * 64 + xx];
      const float v2 = v[(size_t)(e + 2) * 64 + xx];
      const float v3 = v[(size_t)(e + 3) * 64 + xx];
      const float4 p0 = *(const float4*)&S[(cq * 2 + 0) * 1024 + e];
      const float4 p1 = *(const float4*)&S[(cq * 2 + 1) * 1024 + e];
      a0 += p0.x * v0 + p0.y * v1 + p0.z * v2 + p0.w * v3;
      a1 += p1.x * v0 + p1.y * v1 + p1.z * v2 + p1.w * v3;
    }
    #pragma unroll
    for (int jr = 0; jr < 2; ++jr) {
      const int c = c0 + cq * 2 + jr;
      const float val = ((jr == 0) ? a0 : a1) / lrow[cq * 2 + jr];
      out[((size_t)bn * 256 + (c >> 2)) * 256 + 64 * (c & 3) + xx] = val;
    }
  }
}

extern "C" void kernel_launch(void* const* d_in, const int* in_sizes, int n_in,
                              void* d_out, int out_size, void* d_ws, size_t ws_size,
                              hipStream_t stream) {
  (void)in_sizes; (void)n_in; (void)out_size; (void)ws_size;
  const float* x      = (const float*)d_in[0];
  const float* conv_w = (const float*)d_in[1];
  const float* conv_b = (const float*)d_in[2];
  const float* qW1 = (const float*)d_in[3];
  const float* qb1 = (const float*)d_in[4];
  const float* qW2 = (const float*)d_in[5];
  const float* qb2 = (const float*)d_in[6];
  const float* kW1 = (const float*)d_in[7];
  const float* kb1 = (const float*)d_in[8];
  const float* kW2 = (const float*)d_in[9];
  const float* kb2 = (const float*)d_in[10];
  const float* vW1 = (const float*)d_in[11];
  const float* vb1 = (const float*)d_in[12];
  const float* vW2 = (const float*)d_in[13];
  const float* vb2 = (const float*)d_in[14];
  const float* temp = (const float*)d_in[15];
  float* ws  = (float*)d_ws;
  float* out = (float*)d_out;

  k1_G<<<dim3(3 * NB * NCI * (NHH / 4) + 3), dim3(64), 0, stream>>>(x, qW1, kW1, vW1, ws);
  k2_mlp<<<dim3(768), dim3(512), 0, stream>>>(conv_w, conv_b,
      qb1, qW2, qb2, kb1, kW2, kb2, vb1, vW2, vb2, ws);
  k3_attn<<<dim3(1024), dim3(256), 0, stream>>>(ws, temp, out);
}

// Round 3
// 231.032 us; speedup vs baseline: 1.5955x; 1.5955x over previous
//
#include <hip/hip_runtime.h>

constexpr int NB  = 2;     // batch
constexpr int NCI = 4;     // conv input channels
constexpr int NHH = 256;   // H
constexpr int NWW = 256;   // W
constexpr int NCT = 1024;  // conv output channels

// workspace layout (floats)
constexpr int G_OFF   = 0;
constexpr int G_SIZE  = 3 * NB * NCI * NHH * 48;   // G[m][b][i][h][dx*16+r]
constexpr int SW1_OFF = G_OFF + G_SIZE;            // 3*16 column sums of W1
constexpr int Q_OFF   = SW1_OFF + 48;
constexpr int QKV_ONE = NB * 4 * NCT * 64;         // 524288
constexpr int K_OFF   = Q_OFF + QKV_ONE;           // k stored transposed [x][o]
constexpr int V_OFF   = K_OFF + QKV_ONE;

__device__ __forceinline__ float sigmoid_f(float v) {
  return __builtin_amdgcn_rcpf(1.0f + __expf(-v));
}

// K1: G[m][b][i][h][dx*16+r] = sum_w x_pad[b,i,h,w+dx-1] * W1_m[w,r]
// grid: 3*NB*NCI*(NHH/4) + 3, block 64   (unchanged)
__global__ __launch_bounds__(64) void k1_G(
    const float* __restrict__ x,
    const float* __restrict__ qW1, const float* __restrict__ kW1,
    const float* __restrict__ vW1, float* __restrict__ ws) {
  const int tid = threadIdx.x;
  const int NBLK = 3 * NB * NCI * (NHH / 4);
  int bid = blockIdx.x;
  if (bid >= NBLK) {  // column sums of W1 (for conv_b term)
    int m = bid - NBLK;
    if (tid < 16) {
      const float* W1 = (m == 0) ? qW1 : (m == 1) ? kW1 : vW1;
      float s = 0.f;
      for (int w = 0; w < 256; ++w) s += W1[w * 16 + tid];
      ws[SW1_OFF + m * 16 + tid] = s;
    }
    return;
  }
  const int m  = bid / (NB * NCI * (NHH / 4));
  int rem      = bid % (NB * NCI * (NHH / 4));
  const int b  = rem / (NCI * (NHH / 4));
  rem          = rem % (NCI * (NHH / 4));
  const int i  = rem / (NHH / 4);
  const int h0 = (rem % (NHH / 4)) * 4;

  const float* W1 = (m == 0) ? qW1 : (m == 1) ? kW1 : vW1;

  __shared__ float W1l[16 * 260];
  __shared__ float xlb[4][260];

  for (int idx4 = tid; idx4 < 1024; idx4 += 64) {
    const float4 t = ((const float4*)W1)[idx4];
    const int w = idx4 >> 2, r0 = (idx4 & 3) * 4;
    W1l[(r0 + 0) * 260 + w] = t.x;
    W1l[(r0 + 1) * 260 + w] = t.y;
    W1l[(r0 + 2) * 260 + w] = t.z;
    W1l[(r0 + 3) * 260 + w] = t.w;
  }
  const float* xbase = x + ((size_t)(b * NCI + i) * NHH + h0) * NWW;
  for (int idx = tid; idx < 4 * 256; idx += 64) {
    const int rr = idx >> 8, w = idx & 255;
    xlb[rr][1 + w] = xbase[rr * NWW + w];
  }
  if (tid < 4) {
    xlb[tid][0] = 0.f; xlb[tid][257] = 0.f; xlb[tid][258] = 0.f; xlb[tid][259] = 0.f;
  }
  __syncthreads();

  const int wc = tid >> 4, r = tid & 15;
  const int w0 = wc * 64;
  float* Gw = ws + G_OFF + ((size_t)(m * NB + b) * NCI + i) * NHH * 48;
  #pragma unroll
  for (int rr = 0; rr < 4; ++rr) {
    const float* xl = xlb[rr];
    float a0 = 0.f, a1 = 0.f, a2 = 0.f;
    float4 cur = *(const float4*)&xl[w0];
    #pragma unroll 4
    for (int w = w0; w < w0 + 64; w += 4) {
      const float4 nxt = *(const float4*)&xl[w + 4];
      const float4 w1  = *(const float4*)&W1l[r * 260 + w];
      a0 += w1.x * cur.x + w1.y * cur.y + w1.z * cur.z + w1.w * cur.w;
      a1 += w1.x * cur.y + w1.y * cur.z + w1.z * cur.w + w1.w * nxt.x;
      a2 += w1.x * cur.z + w1.y * cur.w + w1.z * nxt.x + w1.w * nxt.y;
      cur = nxt;
    }
    a0 += __shfl_xor(a0, 16, 64); a0 += __shfl_xor(a0, 32, 64);
    a1 += __shfl_xor(a1, 16, 64); a1 += __shfl_xor(a1, 32, 64);
    a2 += __shfl_xor(a2, 16, 64); a2 += __shfl_xor(a2, 32, 64);
    if (wc == 0) {
      float* g = Gw + (size_t)(h0 + rr) * 48;
      g[r] = a0; g[16 + r] = a1; g[32 + r] = a2;
    }
  }
}

// K2: layer1 (conv x W1, K=36, cw via scalar loads) + in-register layer2.
// grid 768 = NB*3*128 (8 o per block), block 512 = 8 waves.
// R3 fix: FULL unroll on i/j loops (rule #20: no runtime-indexed reg arrays),
//         div/mod-free staging.
__global__ __launch_bounds__(512) void k2_mlp(
    const float* __restrict__ conv_w, const float* __restrict__ conv_b,
    const float* __restrict__ qb1, const float* __restrict__ qW2, const float* __restrict__ qb2,
    const float* __restrict__ kb1, const float* __restrict__ kW2, const float* __restrict__ kb2,
    const float* __restrict__ vb1, const float* __restrict__ vW2, const float* __restrict__ vb2,
    float* __restrict__ ws) {
  const int tid = threadIdx.x;
  const int bid = blockIdx.x;
  const int og = bid & 127;
  const int m  = (bid >> 7) % 3;
  const int b  = bid / 384;
  const int o0 = og * 8;

  const int w    = tid >> 6;        // wave 0..7
  const int lane = tid & 63;
  const int hc   = lane >> 4;       // 0..3
  const int r    = lane & 15;

  const float* b1 = (m == 0) ? qb1 : (m == 1) ? kb1 : vb1;
  const float* W2 = (m == 0) ? qW2 : (m == 1) ? kW2 : vW2;
  const float* b2 = (m == 0) ? qb2 : (m == 1) ? kb2 : vb2;

  __shared__ float LDS[12296];
  float* Gl  = LDS;            // [i][34][49]  (i-stride 1666, row-stride 49)
  float* y1l = LDS + 6664;     // [o][32][17]  (o-stride 544)
  float* W2l = LDS + 11016;    // [2][32][20]

  const float* Gbase = ws + G_OFF + (size_t)(m * 2 + b) * (4 * 256 * 48);
  const float sw1r = ws[SW1_OFF + m * 16 + r];
  const float b1r  = b1[r];
  const float* cw_base = conv_w + (size_t)o0 * 36;   // wave-uniform -> s_load
  float cb[8];
  #pragma unroll
  for (int j = 0; j < 8; ++j) cb[j] = conv_b[o0 + j];

  // phase-2 mapping
  const int p2_o  = tid >> 6;
  const int p2_r  = (tid >> 2) & 15;
  const int p2_sq = tid & 3;

  float acc2[4] = {0.f, 0.f, 0.f, 0.f};

  const int hl = w * 4 + hc;

  for (int t = 0; t < 8; ++t) {
    const int h0 = t * 32;
    float* W2b = W2l + (t & 1) * 640;

    // stage G slab (rows h0-1 .. h0+32, zero-padded at edges); no div/mod
    #pragma unroll
    for (int i = 0; i < 4; ++i) {
      for (int row = w; row < 34; row += 8) {
        if (lane < 48) {
          const int h = h0 - 1 + row;
          const float v = (h >= 0 && h < 256)
              ? Gbase[((size_t)i * 256 + h) * 48 + lane] : 0.f;
          Gl[i * 1666 + row * 49 + lane] = v;
        }
      }
    }
    { // stage W2 tile
      const int hh = tid >> 4, s = tid & 15;
      W2b[hh * 20 + s] = W2[(h0 + hh) * 16 + s];
    }
    __syncthreads();

    // phase 1: pre-activation for 8 o's at column (h = h0 + hl, r) — fully static
    {
      float acc[8];
      #pragma unroll
      for (int j = 0; j < 8; ++j) acc[j] = cb[j] * sw1r + b1r;
      const float* gl = Gl + hl * 49 + r;
      #pragma unroll
      for (int i = 0; i < 4; ++i) {
        float g[9];
        #pragma unroll
        for (int dy = 0; dy < 3; ++dy)
          #pragma unroll
          for (int dx = 0; dx < 3; ++dx)
            g[dy * 3 + dx] = gl[i * 1666 + dy * 49 + dx * 16];
        #pragma unroll
        for (int j = 0; j < 8; ++j) {
          const float* cwp = cw_base + j * 36 + i * 9;
          #pragma unroll
          for (int q = 0; q < 9; ++q) acc[j] += cwp[q] * g[q];
        }
      }
      #pragma unroll
      for (int j = 0; j < 8; ++j) y1l[j * 544 + hl * 17 + r] = sigmoid_f(acc[j]);
    }
    __syncthreads();

    // phase 2: contract y1 over the 32 h of this tile into acc2
    {
      const float* yb = y1l + p2_o * 544 + p2_r;
      const float* wb = W2b + p2_sq * 4;
      #pragma unroll 4
      for (int hh = 0; hh < 32; ++hh) {
        const float y = yb[hh * 17];
        const float4 wv = *(const float4*)&wb[hh * 20];
        acc2[0] += y * wv.x; acc2[1] += y * wv.y;
        acc2[2] += y * wv.z; acc2[3] += y * wv.w;
      }
    }
    // no barrier needed: next staging writes Gl only; phase2 read y1l/W2b only
  }

  // epilogue: y2 -> LDS (reuse Gl region) -> coalesced global writes
  #pragma unroll
  for (int j = 0; j < 4; ++j) {
    const int s = p2_sq * 4 + j;
    const float y2 = sigmoid_f(acc2[j] + b2[s]);
    const int n   = (j & 1) * 2 + (p2_r & 1);
    const int xsp = (p2_sq * 2 + (j >> 1)) * 8 + (p2_r >> 1);
    LDS[p2_o * 256 + n * 64 + xsp] = y2;   // y2l[o_loc][n][xsp]
  }
  __syncthreads();

  if (m != 1) {  // q, v: [bn][o][xsp], fully coalesced float4 runs
    float* dst = ws + ((m == 0) ? Q_OFF : V_OFF);
    const int run = tid >> 4, pos = (tid & 15) * 4;
    const int n = run >> 3, o_l = run & 7;
    const float4 v4 = *(const float4*)&LDS[o_l * 256 + n * 64 + pos];
    *(float4*)&dst[((size_t)(b * 4 + n) * 1024 + o0 + o_l) * 64 + pos] = v4;
  } else {       // k: [bn][xsp][o], float4 chunks of 8-o run
    float* dst = ws + K_OFF;
    const int chunk = tid >> 1, half = tid & 1;
    const int n = chunk >> 6, xsp = chunk & 63;
    float4 v4;
    v4.x = LDS[(half * 4 + 0) * 256 + n * 64 + xsp];
    v4.y = LDS[(half * 4 + 1) * 256 + n * 64 + xsp];
    v4.z = LDS[(half * 4 + 2) * 256 + n * 64 + xsp];
    v4.w = LDS[(half * 4 + 3) * 256 + n * 64 + xsp];
    *(float4*)&dst[((size_t)(b * 4 + n) * 64 + xsp) * 1024 + o0 + half * 4] = v4;
  }
}

// K3: per (b,n): scores = q k^T * temp over 64-dim, softmax over e, @ v.
// grid 1024 = 8 bn x 128 row-groups (8 rows), block 256.  (unchanged)
__global__ __launch_bounds__(256) void k3_attn(
    const float* __restrict__ ws, const float* __restrict__ temp,
    float* __restrict__ out) {
  const int tid = threadIdx.x;
  const int bn = blockIdx.x >> 7;
  const int c0 = (blockIdx.x & 127) * 8;
  const float* q  = ws + Q_OFF + (size_t)bn * NCT * 64;
  const float* kT = ws + K_OFF + (size_t)bn * 64 * NCT;
  const float* v  = ws + V_OFF + (size_t)bn * NCT * 64;
  const float tscale = temp[bn & 3];

  __shared__ float S[8 * 1024];
  __shared__ float ql[64 * 8];
  __shared__ float lrow[8];

  for (int j = tid; j < 8 * 64; j += 256) {
    const int c = j >> 6, d = j & 63;
    ql[d * 8 + c] = q[(size_t)(c0 + c) * 64 + d];
  }
  __syncthreads();

  {
    float acc[32];
    #pragma unroll
    for (int j = 0; j < 32; ++j) acc[j] = 0.f;
    for (int d = 0; d < 64; ++d) {
      const float* kr = kT + (size_t)d * NCT;
      const float kv0 = kr[tid];
      const float kv1 = kr[tid + 256];
      const float kv2 = kr[tid + 512];
      const float kv3 = kr[tid + 768];
      #pragma unroll
      for (int c4 = 0; c4 < 2; ++c4) {
        const float4 qv = *(const float4*)&ql[d * 8 + c4 * 4];
        const float qa[4] = {qv.x, qv.y, qv.z, qv.w};
        #pragma unroll
        for (int jj = 0; jj < 4; ++jj) {
          const int cc = c4 * 4 + jj;
          acc[cc * 4 + 0] += qa[jj] * kv0;
          acc[cc * 4 + 1] += qa[jj] * kv1;
          acc[cc * 4 + 2] += qa[jj] * kv2;
          acc[cc * 4 + 3] += qa[jj] * kv3;
        }
      }
    }
    #pragma unroll
    for (int cc = 0; cc < 8; ++cc) {
      S[cc * 1024 + tid      ] = acc[cc * 4 + 0] * tscale;
      S[cc * 1024 + tid + 256] = acc[cc * 4 + 1] * tscale;
      S[cc * 1024 + tid + 512] = acc[cc * 4 + 2] * tscale;
      S[cc * 1024 + tid + 768] = acc[cc * 4 + 3] * tscale;
    }
  }
  __syncthreads();

  {
    const int c = tid >> 5, l = tid & 31;
    float* row = &S[c * 1024];
    float mx = -1e30f;
    for (int j = l; j < 1024; j += 32) mx = fmaxf(mx, row[j]);
    #pragma unroll
    for (int msk = 1; msk < 32; msk <<= 1) mx = fmaxf(mx, __shfl_xor(mx, msk, 64));
    float sum = 0.f;
    for (int j = l; j < 1024; j += 32) {
      const float p = __expf(row[j] - mx);
      row[j] = p;
      sum += p;
    }
    #pragma unroll
    for (int msk = 1; msk < 32; msk <<= 1) sum += __shfl_xor(sum, msk, 64);
    if (l == 0) lrow[c] = sum;
  }
  __syncthreads();

  {
    const int xx = tid & 63, cq = tid >> 6;
    float a0 = 0.f, a1 = 0.f;
    for (int e = 0; e < 1024; e += 4) {
      const float v0 = v[(size_t)(e + 0) * 64 + xx];
      const float v1 = v[(size_t)(e + 1) * 64 + xx];
      const float v2 = v[(size_t)(e + 2) * 64 + xx];
      const float v3 = v[(size_t)(e + 3) * 64 + xx];
      const float4 p0 = *(const float4*)&S[(cq * 2 + 0) * 1024 + e];
      const float4 p1 = *(const float4*)&S[(cq * 2 + 1) * 1024 + e];
      a0 += p0.x * v0 + p0.y * v1 + p0.z * v2 + p0.w * v3;
      a1 += p1.x * v0 + p1.y * v1 + p1.z * v2 + p1.w * v3;
    }
    #pragma unroll
    for (int jr = 0; jr < 2; ++jr) {
      const int c = c0 + cq * 2 + jr;
      const float val = ((jr == 0) ? a0 : a1) / lrow[cq * 2 + jr];
      out[((size_t)bn * 256 + (c >> 2)) * 256 + 64 * (c & 3) + xx] = val;
    }
  }
}

extern "C" void kernel_launch(void* const* d_in, const int* in_sizes, int n_in,
                              void* d_out, int out_size, void* d_ws, size_t ws_size,
                              hipStream_t stream) {
  (void)in_sizes; (void)n_in; (void)out_size; (void)ws_size;
  const float* x      = (const float*)d_in[0];
  const float* conv_w = (const float*)d_in[1];
  const float* conv_b = (const float*)d_in[2];
  const float* qW1 = (const float*)d_in[3];
  const float* qb1 = (const float*)d_in[4];
  const float* qW2 = (const float*)d_in[5];
  const float* qb2 = (const float*)d_in[6];
  const float* kW1 = (const float*)d_in[7];
  const float* kb1 = (const float*)d_in[8];
  const float* kW2 = (const float*)d_in[9];
  const float* kb2 = (const float*)d_in[10];
  const float* vW1 = (const float*)d_in[11];
  const float* vb1 = (const float*)d_in[12];
  const float* vW2 = (const float*)d_in[13];
  const float* vb2 = (const float*)d_in[14];
  const float* temp = (const float*)d_in[15];
  float* ws  = (float*)d_ws;
  float* out = (float*)d_out;

  k1_G<<<dim3(3 * NB * NCI * (NHH / 4) + 3), dim3(64), 0, stream>>>(x, qW1, kW1, vW1, ws);
  k2_mlp<<<dim3(768), dim3(512), 0, stream>>>(conv_w, conv_b,
      qb1, qW2, qb2, kb1, kW2, kb2, vb1, vW2, vb2, ws);
  k3_attn<<<dim3(1024), dim3(256), 0, stream>>>(ws, temp, out);
}

// Round 4
// 175.816 us; speedup vs baseline: 2.0966x; 1.3141x over previous
//
#include <hip/hip_runtime.h>

constexpr int NB  = 2;     // batch
constexpr int NCI = 4;     // conv input channels
constexpr int NHH = 256;   // H
constexpr int NWW = 256;   // W
constexpr int NCT = 1024;  // conv output channels

// workspace layout (floats)
// G padded: [m][b][i][258][48], rows 0 and 257 are zeros (h_pad = h+1)
constexpr int G_OFF   = 0;
constexpr int G_ROWS  = 258;
constexpr int G_ISTR  = G_ROWS * 48;               // 12384
constexpr int G_MBSTR = NCI * G_ISTR;              // 49536
constexpr int G_SIZE  = 3 * NB * G_MBSTR;          // 297216
constexpr int SW1_OFF = G_OFF + G_SIZE;            // 3*16 column sums of W1
constexpr int Q_OFF   = SW1_OFF + 48;
constexpr int QKV_ONE = NB * 4 * NCT * 64;         // 524288
constexpr int K_OFF   = Q_OFF + QKV_ONE;           // k stored transposed [x][o]
constexpr int V_OFF   = K_OFF + QKV_ONE;

__device__ __forceinline__ float sigmoid_f(float v) {
  return __builtin_amdgcn_rcpf(1.0f + __expf(-v));
}

// K1: G[m][b][i][h+1][dx*16+r] = sum_w x_pad[b,i,h,w+dx-1] * W1_m[w,r]
// grid: 3*NB*NCI*(NHH/4) + 3, block 64
__global__ __launch_bounds__(64) void k1_G(
    const float* __restrict__ x,
    const float* __restrict__ qW1, const float* __restrict__ kW1,
    const float* __restrict__ vW1, float* __restrict__ ws) {
  const int tid = threadIdx.x;
  const int NBLK = 3 * NB * NCI * (NHH / 4);
  int bid = blockIdx.x;
  if (bid >= NBLK) {  // column sums of W1 (for conv_b term)
    int m = bid - NBLK;
    if (tid < 16) {
      const float* W1 = (m == 0) ? qW1 : (m == 1) ? kW1 : vW1;
      float s = 0.f;
      for (int w = 0; w < 256; ++w) s += W1[w * 16 + tid];
      ws[SW1_OFF + m * 16 + tid] = s;
    }
    return;
  }
  const int m  = bid / (NB * NCI * (NHH / 4));
  int rem      = bid % (NB * NCI * (NHH / 4));
  const int b  = rem / (NCI * (NHH / 4));
  rem          = rem % (NCI * (NHH / 4));
  const int i  = rem / (NHH / 4);
  const int h0 = (rem % (NHH / 4)) * 4;

  const float* W1 = (m == 0) ? qW1 : (m == 1) ? kW1 : vW1;

  __shared__ float W1l[16 * 260];
  __shared__ float xlb[4][260];

  for (int idx4 = tid; idx4 < 1024; idx4 += 64) {
    const float4 t = ((const float4*)W1)[idx4];
    const int w = idx4 >> 2, r0 = (idx4 & 3) * 4;
    W1l[(r0 + 0) * 260 + w] = t.x;
    W1l[(r0 + 1) * 260 + w] = t.y;
    W1l[(r0 + 2) * 260 + w] = t.z;
    W1l[(r0 + 3) * 260 + w] = t.w;
  }
  const float* xbase = x + ((size_t)(b * NCI + i) * NHH + h0) * NWW;
  for (int idx = tid; idx < 4 * 256; idx += 64) {
    const int rr = idx >> 8, w = idx & 255;
    xlb[rr][1 + w] = xbase[rr * NWW + w];
  }
  if (tid < 4) {
    xlb[tid][0] = 0.f; xlb[tid][257] = 0.f; xlb[tid][258] = 0.f; xlb[tid][259] = 0.f;
  }
  __syncthreads();

  const int wc = tid >> 4, r = tid & 15;
  const int w0 = wc * 64;
  float* Gw = ws + G_OFF + (size_t)((m * NB + b) * NCI + i) * G_ISTR;

  // zero the pad rows (padded rows 0 and 257)
  if (h0 == 0   && tid < 48) Gw[tid] = 0.f;
  if (h0 == 252 && tid < 48) Gw[257 * 48 + tid] = 0.f;

  #pragma unroll
  for (int rr = 0; rr < 4; ++rr) {
    const float* xl = xlb[rr];
    float a0 = 0.f, a1 = 0.f, a2 = 0.f;
    float4 cur = *(const float4*)&xl[w0];
    #pragma unroll 4
    for (int w = w0; w < w0 + 64; w += 4) {
      const float4 nxt = *(const float4*)&xl[w + 4];
      const float4 w1  = *(const float4*)&W1l[r * 260 + w];
      a0 += w1.x * cur.x + w1.y * cur.y + w1.z * cur.z + w1.w * cur.w;
      a1 += w1.x * cur.y + w1.y * cur.z + w1.z * cur.w + w1.w * nxt.x;
      a2 += w1.x * cur.z + w1.y * cur.w + w1.z * nxt.x + w1.w * nxt.y;
      cur = nxt;
    }
    a0 += __shfl_xor(a0, 16, 64); a0 += __shfl_xor(a0, 32, 64);
    a1 += __shfl_xor(a1, 16, 64); a1 += __shfl_xor(a1, 32, 64);
    a2 += __shfl_xor(a2, 16, 64); a2 += __shfl_xor(a2, 32, 64);
    if (wc == 0) {
      float* g = Gw + (size_t)(h0 + rr + 1) * 48;   // +1 pad row
      g[r] = a0; g[16 + r] = a1; g[32 + r] = a2;
    }
  }
}

// K2: layer1 (conv x W1, K=36, conv_w via s_load) + layer2 with W2 in SGPRs.
// grid 768 = NB*3*128 (8 o per block), block 512 = 8 waves.
// LDS: Gl[4][34][48] (linear, 2-way banks) + y1l[8 o][32 h x17][16 r] o-stride 552.
__global__ __launch_bounds__(512) void k2_mlp(
    const float* __restrict__ conv_w, const float* __restrict__ conv_b,
    const float* __restrict__ qb1, const float* __restrict__ qW2, const float* __restrict__ qb2,
    const float* __restrict__ kb1, const float* __restrict__ kW2, const float* __restrict__ kb2,
    const float* __restrict__ vb1, const float* __restrict__ vW2, const float* __restrict__ vb2,
    float* __restrict__ ws) {
  const int tid = threadIdx.x;
  const int bid = blockIdx.x;
  const int og = bid & 127;
  const int m  = (bid >> 7) % 3;
  const int b  = bid / 384;
  const int o0 = og * 8;

  const int wv   = tid >> 6;        // wave 0..7
  const int lane = tid & 63;
  const int hc   = lane >> 4;       // 0..3
  const int r    = lane & 15;
  const int hl   = wv * 4 + hc;     // 0..31 (phase-1 column)

  // phase-2 mapping: sq wave-uniform, lanes = 4 o x 16 r
  const int sq    = __builtin_amdgcn_readfirstlane(wv & 3);
  const int o_loc = (wv >> 2) * 4 + hc;   // 0..7

  const float* b1 = (m == 0) ? qb1 : (m == 1) ? kb1 : vb1;
  const float* W2 = (m == 0) ? qW2 : (m == 1) ? kW2 : vW2;
  const float* b2 = (m == 0) ? qb2 : (m == 1) ? kb2 : vb2;

  __shared__ float LDS[10944];
  float* Gl  = LDS;            // [i][34*48=1632] linear, i-stride 1632
  float* y1l = LDS + 6528;     // [o][h*17 + r], o-stride 552

  const float* Gbase = ws + G_OFF + (size_t)(m * NB + b) * G_MBSTR;
  const float sw1r = ws[SW1_OFF + m * 16 + r];
  const float b1r  = b1[r];
  const float* cw_base = conv_w + (size_t)o0 * 36;   // uniform -> s_load
  const float* W2u = W2 + sq * 4;                    // uniform -> s_load
  float cb[8];
  #pragma unroll
  for (int j = 0; j < 8; ++j) cb[j] = conv_b[o0 + j];

  float acc2[4] = {0.f, 0.f, 0.f, 0.f};

  for (int t = 0; t < 8; ++t) {
    const int h0 = t * 32;

    // stage G slab: padded rows h0..h0+33 per i, fully vectorized, no branches
    #pragma unroll
    for (int i = 0; i < 4; ++i) {
      if (tid < 408) {
        const float4 vv = *(const float4*)&Gbase[(size_t)i * G_ISTR + h0 * 48 + tid * 4];
        *(float4*)&Gl[i * 1632 + tid * 4] = vv;
      }
    }
    __syncthreads();

    // phase 1: pre-activation for 8 o's at column (h = h0 + hl, r)
    {
      float acc[8];
      #pragma unroll
      for (int j = 0; j < 8; ++j) acc[j] = cb[j] * sw1r + b1r;
      const float* gl = Gl + hl * 48 + r;
      #pragma unroll
      for (int i = 0; i < 4; ++i) {
        float g[9];
        #pragma unroll
        for (int dy = 0; dy < 3; ++dy)
          #pragma unroll
          for (int dx = 0; dx < 3; ++dx)
            g[dy * 3 + dx] = gl[i * 1632 + dy * 48 + dx * 16];
        #pragma unroll
        for (int j = 0; j < 8; ++j) {
          const float* cwp = cw_base + j * 36 + i * 9;
          #pragma unroll
          for (int q = 0; q < 9; ++q) acc[j] += cwp[q] * g[q];
        }
      }
      #pragma unroll
      for (int j = 0; j < 8; ++j) y1l[j * 552 + hl * 17 + r] = sigmoid_f(acc[j]);
    }
    __syncthreads();

    // phase 2: contract over this tile's 32 h; W2 operands from SGPRs
    {
      const float* yb = y1l + o_loc * 552 + r;
      #pragma unroll
      for (int hh = 0; hh < 32; ++hh) {
        const float y = yb[hh * 17];
        const float4 w2v = *(const float4*)&W2u[(h0 + hh) * 16];  // uniform -> s_load_dwordx4
        acc2[0] += y * w2v.x; acc2[1] += y * w2v.y;
        acc2[2] += y * w2v.z; acc2[3] += y * w2v.w;
      }
    }
    // no barrier: next staging writes Gl; phase2 read y1l only
  }

  // epilogue: y2 -> LDS (Gl region, no overlap with y1l) -> coalesced stores
  #pragma unroll
  for (int j = 0; j < 4; ++j) {
    const int s = sq * 4 + j;
    const float y2 = sigmoid_f(acc2[j] + b2[s]);
    const int n   = (s & 1) * 2 + (r & 1);
    const int xsp = (s >> 1) * 8 + (r >> 1);
    LDS[o_loc * 256 + n * 64 + xsp] = y2;   // y2l[o_loc][n][xsp]
  }
  __syncthreads();

  if (m != 1) {  // q, v: [bn][o][xsp], fully coalesced float4 runs
    float* dst = ws + ((m == 0) ? Q_OFF : V_OFF);
    const int run = tid >> 4, pos = (tid & 15) * 4;
    const int n = run >> 3, o_l = run & 7;
    const float4 v4 = *(const float4*)&LDS[o_l * 256 + n * 64 + pos];
    *(float4*)&dst[((size_t)(b * 4 + n) * 1024 + o0 + o_l) * 64 + pos] = v4;
  } else {       // k: [bn][xsp][o], float4 chunks of 8-o run
    float* dst = ws + K_OFF;
    const int chunk = tid >> 1, half = tid & 1;
    const int n = chunk >> 6, xsp = chunk & 63;
    float4 v4;
    v4.x = LDS[(half * 4 + 0) * 256 + n * 64 + xsp];
    v4.y = LDS[(half * 4 + 1) * 256 + n * 64 + xsp];
    v4.z = LDS[(half * 4 + 2) * 256 + n * 64 + xsp];
    v4.w = LDS[(half * 4 + 3) * 256 + n * 64 + xsp];
    *(float4*)&dst[((size_t)(b * 4 + n) * 64 + xsp) * 1024 + o0 + half * 4] = v4;
  }
}

// K3: per (b,n): scores = q k^T * temp over 64-dim, softmax over e, @ v.
// grid 1024 = 8 bn x 128 row-groups (8 rows), block 256.  (unchanged)
__global__ __launch_bounds__(256) void k3_attn(
    const float* __restrict__ ws, const float* __restrict__ temp,
    float* __restrict__ out) {
  const int tid = threadIdx.x;
  const int bn = blockIdx.x >> 7;
  const int c0 = (blockIdx.x & 127) * 8;
  const float* q  = ws + Q_OFF + (size_t)bn * NCT * 64;
  const float* kT = ws + K_OFF + (size_t)bn * 64 * NCT;
  const float* v  = ws + V_OFF + (size_t)bn * NCT * 64;
  const float tscale = temp[bn & 3];

  __shared__ float S[8 * 1024];
  __shared__ float ql[64 * 8];
  __shared__ float lrow[8];

  for (int j = tid; j < 8 * 64; j += 256) {
    const int c = j >> 6, d = j & 63;
    ql[d * 8 + c] = q[(size_t)(c0 + c) * 64 + d];
  }
  __syncthreads();

  {
    float acc[32];
    #pragma unroll
    for (int j = 0; j < 32; ++j) acc[j] = 0.f;
    for (int d = 0; d < 64; ++d) {
      const float* kr = kT + (size_t)d * NCT;
      const float kv0 = kr[tid];
      const float kv1 = kr[tid + 256];
      const float kv2 = kr[tid + 512];
      const float kv3 = kr[tid + 768];
      #pragma unroll
      for (int c4 = 0; c4 < 2; ++c4) {
        const float4 qv = *(const float4*)&ql[d * 8 + c4 * 4];
        const float qa[4] = {qv.x, qv.y, qv.z, qv.w};
        #pragma unroll
        for (int jj = 0; jj < 4; ++jj) {
          const int cc = c4 * 4 + jj;
          acc[cc * 4 + 0] += qa[jj] * kv0;
          acc[cc * 4 + 1] += qa[jj] * kv1;
          acc[cc * 4 + 2] += qa[jj] * kv2;
          acc[cc * 4 + 3] += qa[jj] * kv3;
        }
      }
    }
    #pragma unroll
    for (int cc = 0; cc < 8; ++cc) {
      S[cc * 1024 + tid      ] = acc[cc * 4 + 0] * tscale;
      S[cc * 1024 + tid + 256] = acc[cc * 4 + 1] * tscale;
      S[cc * 1024 + tid + 512] = acc[cc * 4 + 2] * tscale;
      S[cc * 1024 + tid + 768] = acc[cc * 4 + 3] * tscale;
    }
  }
  __syncthreads();

  {
    const int c = tid >> 5, l = tid & 31;
    float* row = &S[c * 1024];
    float mx = -1e30f;
    for (int j = l; j < 1024; j += 32) mx = fmaxf(mx, row[j]);
    #pragma unroll
    for (int msk = 1; msk < 32; msk <<= 1) mx = fmaxf(mx, __shfl_xor(mx, msk, 64));
    float sum = 0.f;
    for (int j = l; j < 1024; j += 32) {
      const float p = __expf(row[j] - mx);
      row[j] = p;
      sum += p;
    }
    #pragma unroll
    for (int msk = 1; msk < 32; msk <<= 1) sum += __shfl_xor(sum, msk, 64);
    if (l == 0) lrow[c] = sum;
  }
  __syncthreads();

  {
    const int xx = tid & 63, cq = tid >> 6;
    float a0 = 0.f, a1 = 0.f;
    for (int e = 0; e < 1024; e += 4) {
      const float v0 = v[(size_t)(e + 0) * 64 + xx];
      const float v1 = v[(size_t)(e + 1) * 64 + xx];
      const float v2 = v[(size_t)(e + 2) * 64 + xx];
      const float v3 = v[(size_t)(e + 3) * 64 + xx];
      const float4 p0 = *(const float4*)&S[(cq * 2 + 0) * 1024 + e];
      const float4 p1 = *(const float4*)&S[(cq * 2 + 1) * 1024 + e];
      a0 += p0.x * v0 + p0.y * v1 + p0.z * v2 + p0.w * v3;
      a1 += p1.x * v0 + p1.y * v1 + p1.z * v2 + p1.w * v3;
    }
    #pragma unroll
    for (int jr = 0; jr < 2; ++jr) {
      const int c = c0 + cq * 2 + jr;
      const float val = ((jr == 0) ? a0 : a1) / lrow[cq * 2 + jr];
      out[((size_t)bn * 256 + (c >> 2)) * 256 + 64 * (c & 3) + xx] = val;
    }
  }
}

extern "C" void kernel_launch(void* const* d_in, const int* in_sizes, int n_in,
                              void* d_out, int out_size, void* d_ws, size_t ws_size,
                              hipStream_t stream) {
  (void)in_sizes; (void)n_in; (void)out_size; (void)ws_size;
  const float* x      = (const float*)d_in[0];
  const float* conv_w = (const float*)d_in[1];
  const float* conv_b = (const float*)d_in[2];
  const float* qW1 = (const float*)d_in[3];
  const float* qb1 = (const float*)d_in[4];
  const float* qW2 = (const float*)d_in[5];
  const float* qb2 = (const float*)d_in[6];
  const float* kW1 = (const float*)d_in[7];
  const float* kb1 = (const float*)d_in[8];
  const float* kW2 = (const float*)d_in[9];
  const float* kb2 = (const float*)d_in[10];
  const float* vW1 = (const float*)d_in[11];
  const float* vb1 = (const float*)d_in[12];
  const float* vW2 = (const float*)d_in[13];
  const float* vb2 = (const float*)d_in[14];
  const float* temp = (const float*)d_in[15];
  float* ws  = (float*)d_ws;
  float* out = (float*)d_out;

  k1_G<<<dim3(3 * NB * NCI * (NHH / 4) + 3), dim3(64), 0, stream>>>(x, qW1, kW1, vW1, ws);
  k2_mlp<<<dim3(768), dim3(512), 0, stream>>>(conv_w, conv_b,
      qb1, qW2, qb2, kb1, kW2, kb2, vb1, vW2, vb2, ws);
  k3_attn<<<dim3(1024), dim3(256), 0, stream>>>(ws, temp, out);
}